// Round 1
// baseline (368.184 us; speedup 1.0000x reference)
//
#include <hip/hip_runtime.h>

#define BB 32
#define SS 4096
#define HH 512

// ---------------------------------------------------------------------------
// Kernel 1: query[b,o] = sum_h dec[b,h] * W[o,h]
// One wave (64 lanes) per output element. Row = 512 floats = 128 float4;
// each lane loads 2 float4 (coalesced), 8 fma, shuffle-down reduce.
// W is 1 MiB -> L2-resident after first touch; kernel is tiny (~few us).
// ---------------------------------------------------------------------------
__global__ __launch_bounds__(256) void query_kernel(const float* __restrict__ dec,
                                                    const float* __restrict__ W,
                                                    float* __restrict__ q) {
    const int gwave = (blockIdx.x * 256 + threadIdx.x) >> 6;  // 16384 waves
    const int lane  = threadIdx.x & 63;
    const int b = gwave >> 9;    // / 512
    const int o = gwave & 511;

    const float4* wrow = (const float4*)(W  + (size_t)o * HH);
    const float4* drow = (const float4*)(dec + (size_t)b * HH);

    float4 w0 = wrow[lane], w1 = wrow[64 + lane];
    float4 d0 = drow[lane], d1 = drow[64 + lane];

    float s = w0.x*d0.x + w0.y*d0.y + w0.z*d0.z + w0.w*d0.w
            + w1.x*d1.x + w1.y*d1.y + w1.z*d1.z + w1.w*d1.w;

    #pragma unroll
    for (int off = 32; off >= 1; off >>= 1)
        s += __shfl_down(s, off, 64);

    if (lane == 0) q[gwave] = s;
}

// ---------------------------------------------------------------------------
// Kernel 2: fused scores + context. Reads enc_output exactly ONCE (256 MiB).
//   score[b,s] = enc[b,s,:] . q[b,:]
//   out[b,h]  += score[b,s] * enc[b,s,h]
// Block = 256 threads = 4 waves; 32 blocks per batch; each wave owns 32 rows.
// Query fragment (8 floats per lane) loaded once into registers, reused 32x.
// Per row: 2x global_load_dwordx4/lane, 8 fma, 6-step butterfly (all lanes
// get the score), 8 fma into per-lane context accumulators.
// Epilogue: LDS-combine 4 waves, atomicAdd (32 adds per output element).
// ---------------------------------------------------------------------------
__global__ __launch_bounds__(256) void fused_kernel(const float* __restrict__ enc,
                                                    const float* __restrict__ q,
                                                    float* __restrict__ out) {
    const int lane = threadIdx.x & 63;
    const int wave = threadIdx.x >> 6;
    const int b     = blockIdx.x >> 5;   // 32 blocks per batch
    const int chunk = blockIdx.x & 31;   // 32 chunks of 128 rows

    // Query fragment for this lane's columns: [lane*4 .. +4) and [256+lane*4 .. +4)
    const float4* q4 = (const float4*)(q + (size_t)b * HH);
    const float4 q0 = q4[lane];
    const float4 q1 = q4[64 + lane];

    float4 acc0 = {0.f, 0.f, 0.f, 0.f};
    float4 acc1 = {0.f, 0.f, 0.f, 0.f};

    const int rowBase = chunk * 128 + wave * 32;   // each wave: 32 contiguous rows
    const float4* encBase = (const float4*)(enc + ((size_t)b * SS + rowBase) * HH);

    #pragma unroll 2
    for (int r = 0; r < 32; ++r) {
        const float4* erow = encBase + (size_t)r * 128;   // 128 float4 per row
        float4 e0 = erow[lane];
        float4 e1 = erow[64 + lane];

        float dot = e0.x*q0.x + e0.y*q0.y + e0.z*q0.z + e0.w*q0.w
                  + e1.x*q1.x + e1.y*q1.y + e1.z*q1.z + e1.w*q1.w;

        #pragma unroll
        for (int off = 1; off < 64; off <<= 1)
            dot += __shfl_xor(dot, off, 64);

        acc0.x += dot * e0.x; acc0.y += dot * e0.y;
        acc0.z += dot * e0.z; acc0.w += dot * e0.w;
        acc1.x += dot * e1.x; acc1.y += dot * e1.y;
        acc1.z += dot * e1.z; acc1.w += dot * e1.w;
    }

    // Combine the 4 waves' partial context vectors in LDS, then one atomicAdd
    // per column per block.
    __shared__ float cbuf[4][HH];
    float* cw = cbuf[wave];
    const int c0 = lane * 4;
    cw[c0 + 0] = acc0.x; cw[c0 + 1] = acc0.y; cw[c0 + 2] = acc0.z; cw[c0 + 3] = acc0.w;
    cw[256 + c0 + 0] = acc1.x; cw[256 + c0 + 1] = acc1.y;
    cw[256 + c0 + 2] = acc1.z; cw[256 + c0 + 3] = acc1.w;
    __syncthreads();

    for (int c = threadIdx.x; c < HH; c += 256) {
        float v = cbuf[0][c] + cbuf[1][c] + cbuf[2][c] + cbuf[3][c];
        atomicAdd(out + (size_t)b * HH + c, v);
    }
}

extern "C" void kernel_launch(void* const* d_in, const int* in_sizes, int n_in,
                              void* d_out, int out_size, void* d_ws, size_t ws_size,
                              hipStream_t stream) {
    const float* enc = (const float*)d_in[0];  // [B, S, H]
    const float* dec = (const float*)d_in[1];  // [B, 1, H]
    const float* W   = (const float*)d_in[2];  // [H, H]
    float* out = (float*)d_out;                // [B, 1, H] fp32
    float* q   = (float*)d_ws;                 // [B, H] scratch (64 KiB)

    // d_out is poisoned to 0xAA before every launch; we accumulate with
    // atomics, so zero it first (async memset is graph-capture safe).
    hipMemsetAsync(d_out, 0, (size_t)BB * HH * sizeof(float), stream);

    // 16384 output elements, 1 wave each, 4 waves/block -> 4096 blocks
    query_kernel<<<dim3(4096), dim3(256), 0, stream>>>(dec, W, q);

    // 32 batches x 32 chunks = 1024 blocks
    fused_kernel<<<dim3(1024), dim3(256), 0, stream>>>(enc, q, out);
}

// Round 3
// 342.131 us; speedup vs baseline: 1.0761x; 1.0761x over previous
//
#include <hip/hip_runtime.h>

#define BB 32
#define SS 4096
#define HH 512

typedef float f4 __attribute__((ext_vector_type(4)));   // native vec type:
// required by __builtin_nontemporal_load (HIP_vector_type float4 is rejected)

// ---------------------------------------------------------------------------
// Kernel 1: query[b,o] = sum_h dec[b,h] * W[o,h]
// One wave (64 lanes) per output element; float4 coalesced, shuffle reduce.
// W (1 MiB) + dec (64 KiB) are L2-resident; kernel is a few us.
// ---------------------------------------------------------------------------
__global__ __launch_bounds__(256) void query_kernel(const float* __restrict__ dec,
                                                    const float* __restrict__ W,
                                                    float* __restrict__ q) {
    const int gwave = (blockIdx.x * 256 + threadIdx.x) >> 6;  // 16384 waves
    const int lane  = threadIdx.x & 63;
    const int b = gwave >> 9;    // / 512
    const int o = gwave & 511;

    const f4* wrow = (const f4*)(W  + (size_t)o * HH);
    const f4* drow = (const f4*)(dec + (size_t)b * HH);

    f4 w0 = wrow[lane], w1 = wrow[64 + lane];
    f4 d0 = drow[lane], d1 = drow[64 + lane];

    float s = w0.x*d0.x + w0.y*d0.y + w0.z*d0.z + w0.w*d0.w
            + w1.x*d1.x + w1.y*d1.y + w1.z*d1.z + w1.w*d1.w;

    #pragma unroll
    for (int off = 32; off >= 1; off >>= 1)
        s += __shfl_down(s, off, 64);

    if (lane == 0) q[gwave] = s;
}

// ---------------------------------------------------------------------------
// Kernel 2: fused scores + context. Reads enc_output exactly ONCE (256 MiB).
//   score[b,s] = enc[b,s,:] . q[b,:]
//   out[b,h]  += score[b,s] * enc[b,s,h]
// 2048 blocks (8/CU, fills all 8 wave slots/SIMD), 256 thr = 4 waves/block.
// Each wave owns 16 rows, processed in batches of 4 so the four 6-step
// shuffle-broadcast chains interleave (hides ds_swizzle latency) and 8
// nontemporal dwordx4 loads are in flight per wave (enc is streamed once —
// bypass L2 pollution).
// ---------------------------------------------------------------------------
__global__ __launch_bounds__(256) void fused_kernel(const float* __restrict__ enc,
                                                    const float* __restrict__ q,
                                                    float* __restrict__ out) {
    const int lane = threadIdx.x & 63;
    const int wave = threadIdx.x >> 6;
    const int b     = blockIdx.x >> 6;   // 64 blocks per batch
    const int chunk = blockIdx.x & 63;   // 64 chunks of 64 rows

    const f4* q4 = (const f4*)(q + (size_t)b * HH);
    const f4 q0 = q4[lane];
    const f4 q1 = q4[64 + lane];

    f4 acc0 = {0.f, 0.f, 0.f, 0.f};
    f4 acc1 = {0.f, 0.f, 0.f, 0.f};

    const int rowBase = chunk * 64 + wave * 16;   // each wave: 16 contiguous rows
    const f4* encBase = (const f4*)(enc + ((size_t)b * SS + rowBase) * HH);

    for (int rb = 0; rb < 16; rb += 4) {
        f4 e0[4], e1[4];
        #pragma unroll
        for (int r = 0; r < 4; ++r) {
            const f4* erow = encBase + (size_t)(rb + r) * 128;
            e0[r] = __builtin_nontemporal_load(erow + lane);
            e1[r] = __builtin_nontemporal_load(erow + 64 + lane);
        }

        float dot[4];
        #pragma unroll
        for (int r = 0; r < 4; ++r)
            dot[r] = e0[r].x*q0.x + e0[r].y*q0.y + e0[r].z*q0.z + e0[r].w*q0.w
                   + e1[r].x*q1.x + e1[r].y*q1.y + e1[r].z*q1.z + e1[r].w*q1.w;

        // 4 independent butterfly chains, interleaved
        #pragma unroll
        for (int off = 1; off < 64; off <<= 1) {
            #pragma unroll
            for (int r = 0; r < 4; ++r)
                dot[r] += __shfl_xor(dot[r], off, 64);
        }

        #pragma unroll
        for (int r = 0; r < 4; ++r) {
            acc0.x += dot[r] * e0[r].x; acc0.y += dot[r] * e0[r].y;
            acc0.z += dot[r] * e0[r].z; acc0.w += dot[r] * e0[r].w;
            acc1.x += dot[r] * e1[r].x; acc1.y += dot[r] * e1[r].y;
            acc1.z += dot[r] * e1[r].z; acc1.w += dot[r] * e1[r].w;
        }
    }

    // Combine the 4 waves' partial context vectors in LDS, then one atomicAdd
    // per column per block (64 adds per output element across the grid).
    __shared__ float cbuf[4][HH];
    float* cw = cbuf[wave];
    ((f4*)(cw))[lane]       = acc0;
    ((f4*)(cw + 256))[lane] = acc1;
    __syncthreads();

    for (int c = threadIdx.x; c < HH; c += 256) {
        float v = cbuf[0][c] + cbuf[1][c] + cbuf[2][c] + cbuf[3][c];
        atomicAdd(out + (size_t)b * HH + c, v);
    }
}

extern "C" void kernel_launch(void* const* d_in, const int* in_sizes, int n_in,
                              void* d_out, int out_size, void* d_ws, size_t ws_size,
                              hipStream_t stream) {
    const float* enc = (const float*)d_in[0];  // [B, S, H]
    const float* dec = (const float*)d_in[1];  // [B, 1, H]
    const float* W   = (const float*)d_in[2];  // [H, H]
    float* out = (float*)d_out;                // [B, 1, H] fp32
    float* q   = (float*)d_ws;                 // [B, H] scratch (64 KiB)

    // d_out is poisoned to 0xAA before every launch; we accumulate with
    // atomics, so zero it first (async memset is graph-capture safe).
    (void)hipMemsetAsync(d_out, 0, (size_t)BB * HH * sizeof(float), stream);

    // 16384 output elements, 1 wave each, 4 waves/block -> 4096 blocks
    query_kernel<<<dim3(4096), dim3(256), 0, stream>>>(dec, W, q);

    // 32 batches x 64 chunks = 2048 blocks
    fused_kernel<<<dim3(2048), dim3(256), 0, stream>>>(enc, q, out);
}